// Round 8
// baseline (291.199 us; speedup 1.0000x reference)
//
#include <hip/hip_runtime.h>
#include <hip/hip_bf16.h>
#include <cstdint>
#include <cstddef>

#define S_LEN   4096
#define BATCHN  4
#define DMODEL  1024
#define NHEADS  16
#define HDIM    64
#define MROWS   (S_LEN*BATCHN)   // 16384
#define KDIM    1024
#define KSPLIT  8

typedef __bf16 bf16;
typedef bf16 bf16x8 __attribute__((ext_vector_type(8)));
typedef bf16 bf16x4 __attribute__((ext_vector_type(4)));
typedef float f32x4 __attribute__((ext_vector_type(4)));

#define MFMA16(a,b,c) __builtin_amdgcn_mfma_f32_16x16x32_bf16(a,b,c,0,0,0)

__device__ __forceinline__ void gll16(const void* g, void* l) {
  __builtin_amdgcn_global_load_lds((const __attribute__((address_space(1))) unsigned*)g,
                                   (__attribute__((address_space(3))) unsigned*)l,
                                   16, 0, 0);
}

// ---------------- cast fp32 [S][B][D] -> bf16 [B][S][D] for h and x ----------------
__global__ __launch_bounds__(256) void cast_perm(const float* __restrict__ h,
                                                 const float* __restrict__ x,
                                                 bf16* __restrict__ hb,
                                                 bf16* __restrict__ xb) {
  const int n = MROWS * KDIM;
  int stride = gridDim.x * blockDim.x * 4;
  for (int i = (blockIdx.x * blockDim.x + threadIdx.x) * 4; i < n; i += stride) {
    int s = i >> 12, b = (i >> 10) & 3, d = i & 1023;
    size_t o = ((size_t)(b * S_LEN + s) << 10) | d;
    float4 f = *(const float4*)(h + i);
    bf16x4 u; u[0]=(bf16)f.x; u[1]=(bf16)f.y; u[2]=(bf16)f.z; u[3]=(bf16)f.w;
    *(bf16x4*)(hb + o) = u;
    float4 g = *(const float4*)(x + i);
    bf16x4 v; v[0]=(bf16)g.x; v[1]=(bf16)g.y; v[2]=(bf16)g.z; v[3]=(bf16)g.w;
    *(bf16x4*)(xb + o) = v;
  }
}

// all four weight matrices -> contiguous wcat(3M: Wq|Wk|Wv) | wob(1M)
__global__ __launch_bounds__(256) void cast_w(const float* __restrict__ Wq,
                                              const float* __restrict__ Wk,
                                              const float* __restrict__ Wv,
                                              const float* __restrict__ Wo,
                                              bf16* __restrict__ dst) {
  const int n = 4 * 1048576;
  int stride = gridDim.x * blockDim.x * 4;
  for (int i = (blockIdx.x * blockDim.x + threadIdx.x) * 4; i < n; i += stride) {
    int r = i >> 20;
    const float* src = (r < 1) ? (Wq + i) : (r < 2) ? (Wk + i - 1048576)
                     : (r < 3) ? (Wv + i - 2097152) : (Wo + i - 3145728);
    float4 f = *(const float4*)src;
    bf16x4 o; o[0]=(bf16)f.x; o[1]=(bf16)f.y; o[2]=(bf16)f.z; o[3]=(bf16)f.w;
    *(bf16x4*)(dst + i) = o;
  }
}

// ---------------- shared GEMM body (m97 structure + XOR bank swizzle) ----------------
// Computes one 128x128 C-tile of A*B^T into acc[4][4]. A rows at arow0, B rows at brow0.
struct GemmAcc { f32x4 a[4][4]; };

__device__ __forceinline__ void gemm_tile(const bf16* __restrict__ A,
                                          const bf16* __restrict__ Bw,
                                          size_t arow0, size_t brow0,
                                          bf16* As, bf16* Bs, GemmAcc& G) {
  const int tid  = threadIdx.x;
  const int wid  = tid >> 6;
  const int lane = tid & 63;
  const int wm = wid >> 1, wn = wid & 1;
  const int lr = lane >> 2;
  const int lc = lane & 3;
  const int ssrc = (((lc << 4) ^ (((lr >> 1) & 3) << 4)) >> 1);
  const int fhalf = (lane >> 4) << 4;

  for (int k0 = 0; k0 < KDIM; k0 += 32) {
    #pragma unroll
    for (int i = 0; i < 2; ++i) {
      int seg = (wid << 1) | i;
      gll16(A  + (arow0 + seg*16 + lr) * KDIM + k0 + ssrc, As + seg*512);
      gll16(Bw + (brow0 + seg*16 + lr) * KDIM + k0 + ssrc, Bs + seg*512);
    }
    __syncthreads();
    bf16x8 af[4], bfv[4];
    #pragma unroll
    for (int m = 0; m < 4; ++m) {
      int R = wm*64 + m*16 + (lane & 15);
      af[m] = *(const bf16x8*)((const char*)As + R*64 + (fhalf ^ (((R >> 1) & 3) << 4)));
    }
    #pragma unroll
    for (int n = 0; n < 4; ++n) {
      int R = wn*64 + n*16 + (lane & 15);
      bfv[n] = *(const bf16x8*)((const char*)Bs + R*64 + (fhalf ^ (((R >> 1) & 3) << 4)));
    }
    #pragma unroll
    for (int m = 0; m < 4; ++m)
      #pragma unroll
      for (int n = 0; n < 4; ++n)
        G.a[m][n] = MFMA16(af[m], bfv[n], G.a[m][n]);
    __syncthreads();
  }
}

// ---------------- fused projection GEMM: KVT (2048 blocks) + Q (1024 blocks) -----------
// XCD-affinity map: xcd = bid&7, j = bid>>3 (384 per XCD).
//   j <  256: KVT  mtile = j&15 (Wkv rows), ntile = xcd*16 + (j>>4) (xb rows)
//   j >= 256: Q    mtile = xcd*16 + ((j-256)>>3) (hb rows), ntile = (j-256)&7 (Wq rows)
__global__ __launch_bounds__(256) void proj_gemm(
    const bf16* __restrict__ hb, const bf16* __restrict__ xb,
    const bf16* __restrict__ wcat,
    const float* __restrict__ bq, const float* __restrict__ bk,
    const float* __restrict__ bv,
    bf16* __restrict__ qp, bf16* __restrict__ kvt) {
  __shared__ __align__(16) bf16 As[128*32];
  __shared__ __align__(16) bf16 Bs[128*32];
  const int bid = blockIdx.x;
  const int xcd = bid & 7, j = bid >> 3;
  const bool isKV = (j < 256);
  int mtile, ntile;
  const bf16 *A, *Bw;
  if (isKV) {
    mtile = j & 15; ntile = xcd * 16 + (j >> 4);
    A = wcat + 1048576;  Bw = xb;           // A=Wkv[2048][1024], B=xb[16384][1024]
  } else {
    int q = j - 256;
    mtile = xcd * 16 + (q >> 3); ntile = q & 7;
    A = hb;  Bw = wcat;                     // A=hb[16384][1024], B=Wq[1024][1024]
  }

  GemmAcc G = {};
  gemm_tile(A, Bw, (size_t)mtile * 128, (size_t)ntile * 128, As, Bs, G);

  const int tid = threadIdx.x, wid = tid >> 6, lane = tid & 63;
  const int wm = wid >> 1, wn = wid & 1;
  #pragma unroll
  for (int m = 0; m < 4; ++m) {
    int rowb = mtile*128 + wm*64 + m*16 + ((lane >> 4) << 2);
    #pragma unroll
    for (int n = 0; n < 4; ++n) {
      int col = ntile*128 + wn*64 + n*16 + (lane & 15);
      if (isKV) {
        #pragma unroll
        for (int i = 0; i < 4; ++i) {
          int r = rowb + i;                  // output-dim row 0..2047
          float v = G.a[m][n][i] + ((r < 1024) ? bk[r] : bv[r - 1024]);
          if (r < 1024) v = (v > 0.f) ? v + 1.f : __expf(v);   // elu(k)+1
          kvt[(size_t)r*MROWS + col] = (bf16)v;
        }
      } else {
        float bias = bq[col];
        #pragma unroll
        for (int i = 0; i < 4; ++i) {
          float v = G.a[m][n][i] + bias;
          v = (v > 0.f) ? v + 1.f : __expf(v);                 // elu(q)+1
          qp[(size_t)(rowb+i)*DMODEL + col] = (bf16)v;
        }
      }
    }
  }
}

// ---------------- output GEMM: d_out = op @ Wo^T + bo (fp32 out), XCD-affine ----------
__global__ __launch_bounds__(256) void out_gemm(const bf16* __restrict__ op,
                                                const bf16* __restrict__ wob,
                                                const float* __restrict__ bo,
                                                float* __restrict__ Cout) {
  __shared__ __align__(16) bf16 As[128*32];
  __shared__ __align__(16) bf16 Bs[128*32];
  const int bid = blockIdx.x;
  const int xcd = bid & 7, j = bid >> 3;           // 128 per XCD
  const int mtile = xcd * 16 + (j >> 3), ntile = j & 7;

  GemmAcc G = {};
  gemm_tile(op, wob, (size_t)mtile * 128, (size_t)ntile * 128, As, Bs, G);

  const int tid = threadIdx.x, wid = tid >> 6, lane = tid & 63;
  const int wm = wid >> 1, wn = wid & 1;
  #pragma unroll
  for (int m = 0; m < 4; ++m) {
    int rowb = mtile*128 + wm*64 + m*16 + ((lane >> 4) << 2);
    #pragma unroll
    for (int n = 0; n < 4; ++n) {
      int col = ntile*128 + wn*64 + n*16 + (lane & 15);
      float bias = bo[col];
      #pragma unroll
      for (int i = 0; i < 4; ++i)
        Cout[(size_t)(rowb+i)*DMODEL + col] = G.a[m][n][i] + bias;
    }
  }
}

// ---------------- KV[bh][d][v] = sum_s Kp[d][s]*Vp[v][s]; Ksum[bh][d] fused ------------
__global__ __launch_bounds__(256) void kv_gemm(const bf16* __restrict__ kvt,
                                               float* __restrict__ KVg,
                                               float* __restrict__ Ksumg) {
  const int bh = blockIdx.x;
  const int k0base = blockIdx.y * (S_LEN / KSPLIT);
  const int b = bh >> 4, hh = bh & 15;
  const int tid = threadIdx.x, wid = tid >> 6, lane = tid & 63;
  const int wm = wid >> 1, wn = wid & 1;
  __shared__ __align__(16) bf16 Ks[64*64];
  __shared__ __align__(16) bf16 Vs[64*64];
  const bf16* Kh = kvt + (size_t)(hh*64) * MROWS + b * S_LEN;
  const bf16* Vh = kvt + (size_t)(1024 + hh*64) * MROWS + b * S_LEN;
  f32x4 acc[2][2] = {};
  float ksl0 = 0.f, ksl1 = 0.f;

  for (int k0 = k0base; k0 < k0base + S_LEN/KSPLIT; k0 += 64) {
    #pragma unroll
    for (int j = 0; j < 4; ++j) {
      int cchunk = wid*4 + j;
      int r = (cchunk & 7) * 8 + (lane >> 3);
      int colb = (lane & 7) * 16;
      int scol = colb ^ ((r & 7) << 4);
      const bf16* src = (cchunk < 8) ? Kh : Vh;
      bf16* dst = ((cchunk < 8) ? Ks : Vs) + (size_t)(cchunk & 7) * 8 * 64;
      gll16(src + (size_t)r * MROWS + k0 + (scol >> 1), dst);
    }
    __syncthreads();
    #pragma unroll
    for (int ksb = 0; ksb < 2; ++ksb) {
      bf16x8 af[2], bv[2];
      #pragma unroll
      for (int m = 0; m < 2; ++m) {
        int R = wm*32 + m*16 + (lane & 15);
        int cb = (ksb*64 + ((lane >> 4) << 4)) ^ ((R & 7) << 4);
        af[m] = *(const bf16x8*)((const char*)Ks + R*128 + cb);
      }
      #pragma unroll
      for (int n = 0; n < 2; ++n) {
        int R = wn*32 + n*16 + (lane & 15);
        int cb = (ksb*64 + ((lane >> 4) << 4)) ^ ((R & 7) << 4);
        bv[n] = *(const bf16x8*)((const char*)Vs + R*128 + cb);
      }
      if (wn == 0) {
        #pragma unroll
        for (int j = 0; j < 8; ++j) { ksl0 += (float)af[0][j]; ksl1 += (float)af[1][j]; }
      }
      #pragma unroll
      for (int m = 0; m < 2; ++m)
        #pragma unroll
        for (int n = 0; n < 2; ++n)
          acc[m][n] = MFMA16(af[m], bv[n], acc[m][n]);
    }
    __syncthreads();
  }

  #pragma unroll
  for (int m = 0; m < 2; ++m)
    #pragma unroll
    for (int n = 0; n < 2; ++n)
      #pragma unroll
      for (int i = 0; i < 4; ++i) {
        int dd = wm*32 + m*16 + ((lane >> 4) << 2) + i;
        int vv = wn*32 + n*16 + (lane & 15);
        atomicAdd(&KVg[(size_t)bh*4096 + dd*64 + vv], acc[m][n][i]);
      }

  if (wn == 0) {
    float v0 = ksl0, v1 = ksl1;
    v0 += __shfl_xor(v0, 16); v0 += __shfl_xor(v0, 32);
    v1 += __shfl_xor(v1, 16); v1 += __shfl_xor(v1, 32);
    if (lane < 16) {
      atomicAdd(&Ksumg[bh*64 + wm*32 + lane], v0);
      atomicAdd(&Ksumg[bh*64 + wm*32 + 16 + lane], v1);
    }
  }
}

// ---------------- out_pre = (Qp @ KV) / Z ----------------
__global__ __launch_bounds__(256) void attn_out(const bf16* __restrict__ QP,
                                                const float* __restrict__ KVg,
                                                const float* __restrict__ Ksumg,
                                                bf16* __restrict__ OP) {
  const int head = blockIdx.x, stile = blockIdx.y;
  const int b = head >> 4, hh = head & 15;
  const int tid = threadIdx.x;
  const int wid = tid >> 6, lane = tid & 63;
  const int s0 = stile * 128;
  __shared__ __align__(16) bf16 Qs[128*64];
  __shared__ __align__(16) bf16 KVt[64*64];
  __shared__ float ksum_s[64];
  __shared__ float rZ[128];

  const float* KVh = KVg + (size_t)head*4096;
  #pragma unroll
  for (int i = 0; i < 16; ++i) {
    int idx = i*256 + tid;
    int dd = idx >> 6, vv = idx & 63;
    KVt[vv*64 + dd] = (bf16)KVh[idx];
  }
  if (tid < 64) ksum_s[tid] = Ksumg[head*64 + tid];
  #pragma unroll
  for (int p = 0; p < 4; ++p) {
    int row = p*32 + wid*8 + (lane >> 3);
    gll16(QP + ((size_t)(b*S_LEN + s0 + row))*DMODEL + hh*64 + ((lane&7)<<3),
          Qs + (p*32 + wid*8)*64);
  }
  __syncthreads();

  if (tid < 128) {
    float z = 0.f;
    #pragma unroll
    for (int dd = 0; dd < 64; ++dd) z += (float)Qs[tid*64 + dd] * ksum_s[dd];
    rZ[tid] = 1.f / (z + 1e-6f);
  }
  __syncthreads();

  f32x4 acc[2][4] = {};
  #pragma unroll
  for (int ksb = 0; ksb < 2; ++ksb) {
    bf16x8 af[2], bv[4];
    #pragma unroll
    for (int m = 0; m < 2; ++m)
      af[m] = *(const bf16x8*)(Qs + (wid*32 + m*16 + (lane & 15))*64 + ksb*32 + ((lane>>4)<<3));
    #pragma unroll
    for (int n = 0; n < 4; ++n)
      bv[n] = *(const bf16x8*)(KVt + (n*16 + (lane & 15))*64 + ksb*32 + ((lane>>4)<<3));
    #pragma unroll
    for (int m = 0; m < 2; ++m)
      #pragma unroll
      for (int n = 0; n < 4; ++n)
        acc[m][n] = MFMA16(af[m], bv[n], acc[m][n]);
  }

  #pragma unroll
  for (int m = 0; m < 2; ++m)
    #pragma unroll
    for (int n = 0; n < 4; ++n)
      #pragma unroll
      for (int i = 0; i < 4; ++i) {
        int row = wid*32 + m*16 + ((lane >> 4) << 2) + i;
        int vv  = n*16 + (lane & 15);
        float val = acc[m][n][i] * rZ[row];
        OP[((size_t)((s0+row)*BATCHN + b))*DMODEL + hh*64 + vv] = (bf16)val;
      }
}

// ---------------- launch ----------------
extern "C" void kernel_launch(void* const* d_in, const int* in_sizes, int n_in,
                              void* d_out, int out_size, void* d_ws, size_t ws_size,
                              hipStream_t stream) {
  const float* h  = (const float*)d_in[0];
  const float* x  = (const float*)d_in[1];
  const float* Wq = (const float*)d_in[2];
  const float* bq = (const float*)d_in[3];
  const float* Wk = (const float*)d_in[4];
  const float* bk = (const float*)d_in[5];
  const float* Wv = (const float*)d_in[6];
  const float* bv = (const float*)d_in[7];
  const float* Wo = (const float*)d_in[8];
  const float* bo = (const float*)d_in[9];

  char* ws = (char*)d_ws;
  bf16*  hb   = (bf16*)(ws);                    // 33,554,432 B  [B][S][D]
  bf16*  xb   = (bf16*)(ws + 33554432);         // 33,554,432 B  [B][S][D]
  bf16*  wcat = (bf16*)(ws + 67108864);         //  6,291,456 B  Wq|Wk|Wv [3072][1024]
  bf16*  wob  = (bf16*)(ws + 73400320);         //  2,097,152 B  [1024][1024]
  bf16*  qp   = (bf16*)(ws + 75497472);         // 33,554,432 B  [16384 b*s][1024]
  bf16*  kvt  = (bf16*)(ws + 109051904);        // 67,108,864 B  [2048][16384 b*s]
  float* kvb  = (float*)(ws + 176160768);       //  1,048,576 B  [64][64][64]
  float* ksb  = (float*)(ws + 177209344);       //     16,384 B  [64][64]
  bf16*  op   = (bf16*)(ws + 177225728);        // 33,554,432 B  [16384 s*b][1024]

  cast_perm<<<dim3(4096), 256, 0, stream>>>(h, x, hb, xb);
  cast_w<<<dim3(2048), 256, 0, stream>>>(Wq, Wk, Wv, Wo, wcat);

  hipMemsetAsync(kvb, 0, 1048576 + 16384, stream);

  proj_gemm<<<dim3(3072), 256, 0, stream>>>(hb, xb, wcat, bq, bk, bv, qp, kvt);
  kv_gemm<<<dim3(64, KSPLIT), 256, 0, stream>>>(kvt, kvb, ksb);
  attn_out<<<dim3(64, 32), 256, 0, stream>>>(qp, kvb, ksb, op);
  out_gemm<<<dim3(1024), 256, 0, stream>>>(op, wob, bo, (float*)d_out);
}

// Round 9
// 266.763 us; speedup vs baseline: 1.0916x; 1.0916x over previous
//
#include <hip/hip_runtime.h>
#include <hip/hip_bf16.h>
#include <cstdint>
#include <cstddef>

#define S_LEN   4096
#define BATCHN  4
#define DMODEL  1024
#define NHEADS  16
#define HDIM    64
#define MROWS   (S_LEN*BATCHN)   // 16384
#define KDIM    1024
#define KSPLIT  8
#define NTK     (KDIM/32)        // 32 K-steps

typedef __bf16 bf16;
typedef bf16 bf16x8 __attribute__((ext_vector_type(8)));
typedef bf16 bf16x4 __attribute__((ext_vector_type(4)));
typedef float f32x4 __attribute__((ext_vector_type(4)));

#define MFMA16(a,b,c) __builtin_amdgcn_mfma_f32_16x16x32_bf16(a,b,c,0,0,0)

__device__ __forceinline__ void gll16(const void* g, void* l) {
  __builtin_amdgcn_global_load_lds((const __attribute__((address_space(1))) unsigned*)g,
                                   (__attribute__((address_space(3))) unsigned*)l,
                                   16, 0, 0);
}

// ---------------- cast fp32 [S][B][D] -> bf16 [B][S][D] for h and x ----------------
__global__ __launch_bounds__(256) void cast_perm(const float* __restrict__ h,
                                                 const float* __restrict__ x,
                                                 bf16* __restrict__ hb,
                                                 bf16* __restrict__ xb) {
  const int n = MROWS * KDIM;
  int stride = gridDim.x * blockDim.x * 4;
  for (int i = (blockIdx.x * blockDim.x + threadIdx.x) * 4; i < n; i += stride) {
    int s = i >> 12, b = (i >> 10) & 3, d = i & 1023;
    size_t o = ((size_t)(b * S_LEN + s) << 10) | d;
    float4 f = *(const float4*)(h + i);
    bf16x4 u; u[0]=(bf16)f.x; u[1]=(bf16)f.y; u[2]=(bf16)f.z; u[3]=(bf16)f.w;
    *(bf16x4*)(hb + o) = u;
    float4 g = *(const float4*)(x + i);
    bf16x4 v; v[0]=(bf16)g.x; v[1]=(bf16)g.y; v[2]=(bf16)g.z; v[3]=(bf16)g.w;
    *(bf16x4*)(xb + o) = v;
  }
}

// all four weight matrices -> contiguous wcat(3M: Wq|Wk|Wv) | wob(1M)
__global__ __launch_bounds__(256) void cast_w(const float* __restrict__ Wq,
                                              const float* __restrict__ Wk,
                                              const float* __restrict__ Wv,
                                              const float* __restrict__ Wo,
                                              bf16* __restrict__ dst) {
  const int n = 4 * 1048576;
  int stride = gridDim.x * blockDim.x * 4;
  for (int i = (blockIdx.x * blockDim.x + threadIdx.x) * 4; i < n; i += stride) {
    int r = i >> 20;
    const float* src = (r < 1) ? (Wq + i) : (r < 2) ? (Wk + i - 1048576)
                     : (r < 3) ? (Wv + i - 2097152) : (Wo + i - 3145728);
    float4 f = *(const float4*)src;
    bf16x4 o; o[0]=(bf16)f.x; o[1]=(bf16)f.y; o[2]=(bf16)f.z; o[3]=(bf16)f.w;
    *(bf16x4*)(dst + i) = o;
  }
}

// ---------------- shared GEMM body: 3-buffer pipeline, counted vmcnt, XOR swizzle -----
// Per buffer: A[128][32] (8KB) + B[128][32] (8KB). 3 buffers = 48KB -> 3 blocks/CU.
// Ledger: prologue stages t0,t1 (8 loads), vmcnt(4)=t0 done. Iter t: ds_read buf[t%3],
// stage t+2 -> buf[(t+2)%3] (its prior readers finished before iter t-1's end barrier),
// MFMA, then vmcnt(4) (t<NT-2: drains t+1, leaves t+2 in flight) / vmcnt(0) at NT-2.
struct GemmAcc { f32x4 a[4][4]; };

__device__ __forceinline__ void gemm_tile(const bf16* __restrict__ A,
                                          const bf16* __restrict__ Bw,
                                          size_t arow0, size_t brow0,
                                          bf16* sm, GemmAcc& G) {
  const int tid  = threadIdx.x;
  const int wid  = tid >> 6;
  const int lane = tid & 63;
  const int wm = wid >> 1, wn = wid & 1;
  const int lr = lane >> 2;
  const int lc = lane & 3;
  const int ssrc = (((lc << 4) ^ (((lr >> 1) & 3) << 4)) >> 1);
  const int fhalf = (lane >> 4) << 4;

  const bf16* ap[2]; const bf16* bp[2]; int sdo[2];
  #pragma unroll
  for (int i = 0; i < 2; ++i) {
    int seg = (wid << 1) | i;
    ap[i] = A  + (arow0 + seg*16 + lr) * KDIM + ssrc;
    bp[i] = Bw + (brow0 + seg*16 + lr) * KDIM + ssrc;
    sdo[i] = seg * 512;
  }

  // prologue: stage k-steps 0 and 1
  #pragma unroll
  for (int i = 0; i < 2; ++i) { gll16(ap[i],      sm + sdo[i]); gll16(bp[i],      sm + 4096 + sdo[i]); }
  #pragma unroll
  for (int i = 0; i < 2; ++i) { gll16(ap[i] + 32, sm + 8192 + sdo[i]); gll16(bp[i] + 32, sm + 12288 + sdo[i]); }
  asm volatile("s_waitcnt vmcnt(4)" ::: "memory");
  __builtin_amdgcn_s_barrier();
  asm volatile("" ::: "memory");

  int cur = 0;
  for (int t = 0; t < NTK; ++t) {
    const bf16* As = sm + cur * 8192;
    const bf16* Bs = As + 4096;

    bf16x8 af[4], bfv[4];
    #pragma unroll
    for (int m = 0; m < 4; ++m) {
      int R = wm*64 + m*16 + (lane & 15);
      af[m] = *(const bf16x8*)((const char*)As + R*64 + (fhalf ^ (((R >> 1) & 3) << 4)));
    }
    #pragma unroll
    for (int n = 0; n < 4; ++n) {
      int R = wn*64 + n*16 + (lane & 15);
      bfv[n] = *(const bf16x8*)((const char*)Bs + R*64 + (fhalf ^ (((R >> 1) & 3) << 4)));
    }

    if (t + 2 < NTK) {
      int nx2 = cur + 2; if (nx2 >= 3) nx2 -= 3;
      bf16* wbA = sm + nx2 * 8192;
      const int ko = (t + 2) * 32;
      #pragma unroll
      for (int i = 0; i < 2; ++i) {
        gll16(ap[i] + ko, wbA + sdo[i]);
        gll16(bp[i] + ko, wbA + 4096 + sdo[i]);
      }
    }

    #pragma unroll
    for (int m = 0; m < 4; ++m)
      #pragma unroll
      for (int n = 0; n < 4; ++n)
        G.a[m][n] = MFMA16(af[m], bfv[n], G.a[m][n]);

    if (t < NTK - 2)       asm volatile("s_waitcnt vmcnt(4)" ::: "memory");
    else if (t == NTK - 2) asm volatile("s_waitcnt vmcnt(0)" ::: "memory");
    if (t < NTK - 1) {
      __builtin_amdgcn_s_barrier();
      asm volatile("" ::: "memory");
    }
    cur = (cur == 2) ? 0 : cur + 1;
  }
}

// ---------------- GEMM C = A * B^T, three modes (same as R7) ----------------
// MODE 0 (Q):   A=hb[16384][1024], B=Wq,  C=qp bf16, bias bq[col], elu+1 all.
// MODE 1 (KVT): A=Wkv[2048][1024], B=xb,  C=kvt bf16 [2048][16384], row-keyed bias,
//               elu+1 iff row<1024.
// MODE 2 (OUT): A=op[16384][1024], B=Wo,  C=d_out fp32, bias bo[col].
template<int MODE>
__global__ __launch_bounds__(256) void gemm_bt(
    const bf16* __restrict__ A, const bf16* __restrict__ Bw,
    const float* __restrict__ bias0, const float* __restrict__ bias1,
    void* __restrict__ Cout) {
  __shared__ __align__(16) bf16 sm[3 * 8192];   // 48 KB
  const int tid  = threadIdx.x;
  const int wid  = tid >> 6;
  const int lane = tid & 63;
  const int wm = wid >> 1, wn = wid & 1;
  const int mtile = blockIdx.x, ntile = blockIdx.y;
  const int CP = (MODE == 1) ? MROWS : DMODEL;

  GemmAcc G = {};
  gemm_tile(A, Bw, (size_t)mtile * 128, (size_t)ntile * 128, sm, G);

  #pragma unroll
  for (int m = 0; m < 4; ++m) {
    int rowb = mtile*128 + wm*64 + m*16 + ((lane >> 4) << 2);
    #pragma unroll
    for (int n = 0; n < 4; ++n) {
      int col = ntile*128 + wn*64 + n*16 + (lane & 15);
      if (MODE == 0) {
        float bias = bias0[col];
        bf16* C = (bf16*)Cout;
        #pragma unroll
        for (int i = 0; i < 4; ++i) {
          float v = G.a[m][n][i] + bias;
          v = (v > 0.f) ? v + 1.f : __expf(v);          // elu(x)+1
          C[(size_t)(rowb+i)*CP + col] = (bf16)v;
        }
      } else if (MODE == 1) {
        bf16* C = (bf16*)Cout;
        #pragma unroll
        for (int i = 0; i < 4; ++i) {
          int r = rowb + i;
          float v = G.a[m][n][i] + ((r < 1024) ? bias0[r] : bias1[r - 1024]);
          if (r < 1024) v = (v > 0.f) ? v + 1.f : __expf(v);
          C[(size_t)r*CP + col] = (bf16)v;
        }
      } else {
        float bias = bias0[col];
        float* C = (float*)Cout;
        #pragma unroll
        for (int i = 0; i < 4; ++i)
          C[(size_t)(rowb+i)*CP + col] = G.a[m][n][i] + bias;
      }
    }
  }
}

// ---------------- KV[bh][d][v] = sum_s Kp[d][s]*Vp[v][s]; Ksum[bh][d] fused ------------
__global__ __launch_bounds__(256) void kv_gemm(const bf16* __restrict__ kvt,
                                               float* __restrict__ KVg,
                                               float* __restrict__ Ksumg) {
  const int bh = blockIdx.x;
  const int k0base = blockIdx.y * (S_LEN / KSPLIT);
  const int b = bh >> 4, hh = bh & 15;
  const int tid = threadIdx.x, wid = tid >> 6, lane = tid & 63;
  const int wm = wid >> 1, wn = wid & 1;
  __shared__ __align__(16) bf16 Ks[64*64];
  __shared__ __align__(16) bf16 Vs[64*64];
  const bf16* Kh = kvt + (size_t)(hh*64) * MROWS + b * S_LEN;
  const bf16* Vh = kvt + (size_t)(1024 + hh*64) * MROWS + b * S_LEN;
  f32x4 acc[2][2] = {};
  float ksl0 = 0.f, ksl1 = 0.f;

  for (int k0 = k0base; k0 < k0base + S_LEN/KSPLIT; k0 += 64) {
    #pragma unroll
    for (int j = 0; j < 4; ++j) {
      int cchunk = wid*4 + j;
      int r = (cchunk & 7) * 8 + (lane >> 3);
      int colb = (lane & 7) * 16;
      int scol = colb ^ ((r & 7) << 4);
      const bf16* src = (cchunk < 8) ? Kh : Vh;
      bf16* dst = ((cchunk < 8) ? Ks : Vs) + (size_t)(cchunk & 7) * 8 * 64;
      gll16(src + (size_t)r * MROWS + k0 + (scol >> 1), dst);
    }
    __syncthreads();
    #pragma unroll
    for (int ksb = 0; ksb < 2; ++ksb) {
      bf16x8 af[2], bv[2];
      #pragma unroll
      for (int m = 0; m < 2; ++m) {
        int R = wm*32 + m*16 + (lane & 15);
        int cb = (ksb*64 + ((lane >> 4) << 4)) ^ ((R & 7) << 4);
        af[m] = *(const bf16x8*)((const char*)Ks + R*128 + cb);
      }
      #pragma unroll
      for (int n = 0; n < 2; ++n) {
        int R = wn*32 + n*16 + (lane & 15);
        int cb = (ksb*64 + ((lane >> 4) << 4)) ^ ((R & 7) << 4);
        bv[n] = *(const bf16x8*)((const char*)Vs + R*128 + cb);
      }
      if (wn == 0) {
        #pragma unroll
        for (int j = 0; j < 8; ++j) { ksl0 += (float)af[0][j]; ksl1 += (float)af[1][j]; }
      }
      #pragma unroll
      for (int m = 0; m < 2; ++m)
        #pragma unroll
        for (int n = 0; n < 2; ++n)
          acc[m][n] = MFMA16(af[m], bv[n], acc[m][n]);
    }
    __syncthreads();
  }

  #pragma unroll
  for (int m = 0; m < 2; ++m)
    #pragma unroll
    for (int n = 0; n < 2; ++n)
      #pragma unroll
      for (int i = 0; i < 4; ++i) {
        int dd = wm*32 + m*16 + ((lane >> 4) << 2) + i;
        int vv = wn*32 + n*16 + (lane & 15);
        atomicAdd(&KVg[(size_t)bh*4096 + dd*64 + vv], acc[m][n][i]);
      }

  if (wn == 0) {
    float v0 = ksl0, v1 = ksl1;
    v0 += __shfl_xor(v0, 16); v0 += __shfl_xor(v0, 32);
    v1 += __shfl_xor(v1, 16); v1 += __shfl_xor(v1, 32);
    if (lane < 16) {
      atomicAdd(&Ksumg[bh*64 + wm*32 + lane], v0);
      atomicAdd(&Ksumg[bh*64 + wm*32 + 16 + lane], v1);
    }
  }
}

// ---------------- out_pre = (Qp @ KV) / Z ----------------
__global__ __launch_bounds__(256) void attn_out(const bf16* __restrict__ QP,
                                                const float* __restrict__ KVg,
                                                const float* __restrict__ Ksumg,
                                                bf16* __restrict__ OP) {
  const int head = blockIdx.x, stile = blockIdx.y;
  const int b = head >> 4, hh = head & 15;
  const int tid = threadIdx.x;
  const int wid = tid >> 6, lane = tid & 63;
  const int s0 = stile * 128;
  __shared__ __align__(16) bf16 Qs[128*64];
  __shared__ __align__(16) bf16 KVt[64*64];
  __shared__ float ksum_s[64];
  __shared__ float rZ[128];

  const float* KVh = KVg + (size_t)head*4096;
  #pragma unroll
  for (int i = 0; i < 16; ++i) {
    int idx = i*256 + tid;
    int dd = idx >> 6, vv = idx & 63;
    KVt[vv*64 + dd] = (bf16)KVh[idx];
  }
  if (tid < 64) ksum_s[tid] = Ksumg[head*64 + tid];
  #pragma unroll
  for (int p = 0; p < 4; ++p) {
    int row = p*32 + wid*8 + (lane >> 3);
    gll16(QP + ((size_t)(b*S_LEN + s0 + row))*DMODEL + hh*64 + ((lane&7)<<3),
          Qs + (p*32 + wid*8)*64);
  }
  __syncthreads();

  if (tid < 128) {
    float z = 0.f;
    #pragma unroll
    for (int dd = 0; dd < 64; ++dd) z += (float)Qs[tid*64 + dd] * ksum_s[dd];
    rZ[tid] = 1.f / (z + 1e-6f);
  }
  __syncthreads();

  f32x4 acc[2][4] = {};
  #pragma unroll
  for (int ksb = 0; ksb < 2; ++ksb) {
    bf16x8 af[2], bv[4];
    #pragma unroll
    for (int m = 0; m < 2; ++m)
      af[m] = *(const bf16x8*)(Qs + (wid*32 + m*16 + (lane & 15))*64 + ksb*32 + ((lane>>4)<<3));
    #pragma unroll
    for (int n = 0; n < 4; ++n)
      bv[n] = *(const bf16x8*)(KVt + (n*16 + (lane & 15))*64 + ksb*32 + ((lane>>4)<<3));
    #pragma unroll
    for (int m = 0; m < 2; ++m)
      #pragma unroll
      for (int n = 0; n < 4; ++n)
        acc[m][n] = MFMA16(af[m], bv[n], acc[m][n]);
  }

  #pragma unroll
  for (int m = 0; m < 2; ++m)
    #pragma unroll
    for (int n = 0; n < 4; ++n)
      #pragma unroll
      for (int i = 0; i < 4; ++i) {
        int row = wid*32 + m*16 + ((lane >> 4) << 2) + i;
        int vv  = n*16 + (lane & 15);
        float val = acc[m][n][i] * rZ[row];
        OP[((size_t)((s0+row)*BATCHN + b))*DMODEL + hh*64 + vv] = (bf16)val;
      }
}

// ---------------- launch ----------------
extern "C" void kernel_launch(void* const* d_in, const int* in_sizes, int n_in,
                              void* d_out, int out_size, void* d_ws, size_t ws_size,
                              hipStream_t stream) {
  const float* h  = (const float*)d_in[0];
  const float* x  = (const float*)d_in[1];
  const float* Wq = (const float*)d_in[2];
  const float* bq = (const float*)d_in[3];
  const float* Wk = (const float*)d_in[4];
  const float* bk = (const float*)d_in[5];
  const float* Wv = (const float*)d_in[6];
  const float* bv = (const float*)d_in[7];
  const float* Wo = (const float*)d_in[8];
  const float* bo = (const float*)d_in[9];

  char* ws = (char*)d_ws;
  bf16*  hb   = (bf16*)(ws);                    // 33,554,432 B  [B][S][D]
  bf16*  xb   = (bf16*)(ws + 33554432);         // 33,554,432 B  [B][S][D]
  bf16*  wcat = (bf16*)(ws + 67108864);         //  6,291,456 B  Wq|Wk|Wv [3072][1024]
  bf16*  wob  = (bf16*)(ws + 73400320);         //  2,097,152 B  [1024][1024]
  bf16*  qp   = (bf16*)(ws + 75497472);         // 33,554,432 B  [16384 b*s][1024]
  bf16*  kvt  = (bf16*)(ws + 109051904);        // 67,108,864 B  [2048][16384 b*s]
  float* kvb  = (float*)(ws + 176160768);       //  1,048,576 B  [64][64][64]
  float* ksb  = (float*)(ws + 177209344);       //     16,384 B  [64][64]
  bf16*  op   = (bf16*)(ws + 177225728);        // 33,554,432 B  [16384 s*b][1024]

  cast_perm<<<dim3(4096), 256, 0, stream>>>(h, x, hb, xb);
  cast_w<<<dim3(2048), 256, 0, stream>>>(Wq, Wk, Wv, Wo, wcat);

  hipMemsetAsync(kvb, 0, 1048576 + 16384, stream);

  gemm_bt<1><<<dim3(16, 128), 256, 0, stream>>>(wcat + 1048576, xb, bk, bv, kvt);
  gemm_bt<0><<<dim3(128, 8),  256, 0, stream>>>(hb, wcat, bq, nullptr, qp);
  kv_gemm<<<dim3(64, KSPLIT), 256, 0, stream>>>(kvt, kvb, ksb);
  attn_out<<<dim3(64, 32), 256, 0, stream>>>(qp, kvb, ksb, op);
  gemm_bt<2><<<dim3(128, 8), 256, 0, stream>>>(op, wob, bo, nullptr, d_out);
}

// Round 10
// 257.136 us; speedup vs baseline: 1.1325x; 1.0374x over previous
//
#include <hip/hip_runtime.h>
#include <hip/hip_bf16.h>
#include <cstdint>
#include <cstddef>

#define S_LEN   4096
#define BATCHN  4
#define DMODEL  1024
#define NHEADS  16
#define HDIM    64
#define MROWS   (S_LEN*BATCHN)   // 16384
#define KDIM    1024
#define NTK     (KDIM/32)        // 32 K-steps
#define CLP     136              // padded C-tile pitch (elements), 272B = 16B-aligned

typedef __bf16 bf16;
typedef bf16 bf16x8 __attribute__((ext_vector_type(8)));
typedef bf16 bf16x4 __attribute__((ext_vector_type(4)));
typedef float f32x4 __attribute__((ext_vector_type(4)));

#define MFMA16(a,b,c) __builtin_amdgcn_mfma_f32_16x16x32_bf16(a,b,c,0,0,0)

__device__ __forceinline__ void gll16(const void* g, void* l) {
  __builtin_amdgcn_global_load_lds((const __attribute__((address_space(1))) unsigned*)g,
                                   (__attribute__((address_space(3))) unsigned*)l,
                                   16, 0, 0);
}

// ---------------- cast fp32 [S][B][D] -> bf16 [B][S][D] for h and x ----------------
__global__ __launch_bounds__(256) void cast_perm(const float* __restrict__ h,
                                                 const float* __restrict__ x,
                                                 bf16* __restrict__ hb,
                                                 bf16* __restrict__ xb) {
  const int n = MROWS * KDIM;
  int stride = gridDim.x * blockDim.x * 4;
  for (int i = (blockIdx.x * blockDim.x + threadIdx.x) * 4; i < n; i += stride) {
    int s = i >> 12, b = (i >> 10) & 3, d = i & 1023;
    size_t o = ((size_t)(b * S_LEN + s) << 10) | d;
    float4 f = *(const float4*)(h + i);
    bf16x4 u; u[0]=(bf16)f.x; u[1]=(bf16)f.y; u[2]=(bf16)f.z; u[3]=(bf16)f.w;
    *(bf16x4*)(hb + o) = u;
    float4 g = *(const float4*)(x + i);
    bf16x4 v; v[0]=(bf16)g.x; v[1]=(bf16)g.y; v[2]=(bf16)g.z; v[3]=(bf16)g.w;
    *(bf16x4*)(xb + o) = v;
  }
}

// all four weight matrices -> contiguous wcat(3M: Wq|Wk|Wv) | wob(1M)
__global__ __launch_bounds__(256) void cast_w(const float* __restrict__ Wq,
                                              const float* __restrict__ Wk,
                                              const float* __restrict__ Wv,
                                              const float* __restrict__ Wo,
                                              bf16* __restrict__ dst) {
  const int n = 4 * 1048576;
  int stride = gridDim.x * blockDim.x * 4;
  for (int i = (blockIdx.x * blockDim.x + threadIdx.x) * 4; i < n; i += stride) {
    int r = i >> 20;
    const float* src = (r < 1) ? (Wq + i) : (r < 2) ? (Wk + i - 1048576)
                     : (r < 3) ? (Wv + i - 2097152) : (Wo + i - 3145728);
    float4 f = *(const float4*)src;
    bf16x4 o; o[0]=(bf16)f.x; o[1]=(bf16)f.y; o[2]=(bf16)f.z; o[3]=(bf16)f.w;
    *(bf16x4*)(dst + i) = o;
  }
}

// ---------------- shared GEMM body: 3-buffer pipeline, counted vmcnt, XOR swizzle -----
struct GemmAcc { f32x4 a[4][4]; };

__device__ __forceinline__ void gemm_tile(const bf16* __restrict__ A,
                                          const bf16* __restrict__ Bw,
                                          size_t arow0, size_t brow0,
                                          bf16* sm, GemmAcc& G) {
  const int tid  = threadIdx.x;
  const int wid  = tid >> 6;
  const int lane = tid & 63;
  const int wm = wid >> 1, wn = wid & 1;
  const int lr = lane >> 2;
  const int lc = lane & 3;
  const int ssrc = (((lc << 4) ^ (((lr >> 1) & 3) << 4)) >> 1);
  const int fhalf = (lane >> 4) << 4;

  const bf16* ap[2]; const bf16* bp[2]; int sdo[2];
  #pragma unroll
  for (int i = 0; i < 2; ++i) {
    int seg = (wid << 1) | i;
    ap[i] = A  + (arow0 + seg*16 + lr) * KDIM + ssrc;
    bp[i] = Bw + (brow0 + seg*16 + lr) * KDIM + ssrc;
    sdo[i] = seg * 512;
  }

  #pragma unroll
  for (int i = 0; i < 2; ++i) { gll16(ap[i],      sm + sdo[i]); gll16(bp[i],      sm + 4096 + sdo[i]); }
  #pragma unroll
  for (int i = 0; i < 2; ++i) { gll16(ap[i] + 32, sm + 8192 + sdo[i]); gll16(bp[i] + 32, sm + 12288 + sdo[i]); }
  asm volatile("s_waitcnt vmcnt(4)" ::: "memory");
  __builtin_amdgcn_s_barrier();
  asm volatile("" ::: "memory");

  int cur = 0;
  for (int t = 0; t < NTK; ++t) {
    const bf16* As = sm + cur * 8192;
    const bf16* Bs = As + 4096;

    bf16x8 af[4], bfv[4];
    #pragma unroll
    for (int m = 0; m < 4; ++m) {
      int R = wm*64 + m*16 + (lane & 15);
      af[m] = *(const bf16x8*)((const char*)As + R*64 + (fhalf ^ (((R >> 1) & 3) << 4)));
    }
    #pragma unroll
    for (int n = 0; n < 4; ++n) {
      int R = wn*64 + n*16 + (lane & 15);
      bfv[n] = *(const bf16x8*)((const char*)Bs + R*64 + (fhalf ^ (((R >> 1) & 3) << 4)));
    }

    if (t + 2 < NTK) {
      int nx2 = cur + 2; if (nx2 >= 3) nx2 -= 3;
      bf16* wbA = sm + nx2 * 8192;
      const int ko = (t + 2) * 32;
      #pragma unroll
      for (int i = 0; i < 2; ++i) {
        gll16(ap[i] + ko, wbA + sdo[i]);
        gll16(bp[i] + ko, wbA + 4096 + sdo[i]);
      }
    }

    #pragma unroll
    for (int m = 0; m < 4; ++m)
      #pragma unroll
      for (int n = 0; n < 4; ++n)
        G.a[m][n] = MFMA16(af[m], bfv[n], G.a[m][n]);

    if (t < NTK - 2)       asm volatile("s_waitcnt vmcnt(4)" ::: "memory");
    else if (t == NTK - 2) asm volatile("s_waitcnt vmcnt(0)" ::: "memory");
    if (t < NTK - 1) {
      __builtin_amdgcn_s_barrier();
      asm volatile("" ::: "memory");
    }
    cur = (cur == 2) ? 0 : cur + 1;
  }
}

// ---------------- GEMM C = A * B^T, modes 0 (Q) and 2 (OUT) ----------------
template<int MODE>
__global__ __launch_bounds__(256) void gemm_bt(
    const bf16* __restrict__ A, const bf16* __restrict__ Bw,
    const float* __restrict__ bias0,
    void* __restrict__ Cout) {
  __shared__ __align__(16) bf16 sm[3 * 8192];   // 48 KB
  const int tid  = threadIdx.x;
  const int wid  = tid >> 6;
  const int lane = tid & 63;
  const int wm = wid >> 1, wn = wid & 1;
  const int mtile = blockIdx.x, ntile = blockIdx.y;

  GemmAcc G = {};
  gemm_tile(A, Bw, (size_t)mtile * 128, (size_t)ntile * 128, sm, G);

  #pragma unroll
  for (int m = 0; m < 4; ++m) {
    int rowb = mtile*128 + wm*64 + m*16 + ((lane >> 4) << 2);
    #pragma unroll
    for (int n = 0; n < 4; ++n) {
      int col = ntile*128 + wn*64 + n*16 + (lane & 15);
      float bias = bias0[col];
      if (MODE == 0) {
        bf16* C = (bf16*)Cout;
        #pragma unroll
        for (int i = 0; i < 4; ++i) {
          float v = G.a[m][n][i] + bias;
          v = (v > 0.f) ? v + 1.f : __expf(v);          // elu(x)+1
          C[(size_t)(rowb+i)*DMODEL + col] = (bf16)v;
        }
      } else {
        float* C = (float*)Cout;
        #pragma unroll
        for (int i = 0; i < 4; ++i)
          C[(size_t)(rowb+i)*DMODEL + col] = G.a[m][n][i] + bias;
      }
    }
  }
}

// ---------------- fused KV projection + KV/Ksum reduction ----------------
// grid (8 m, 128 ntile), 512 threads (8 waves: wm=wid>>1 in 0..3 over 256 A-rows,
// wn=wid&1 over 128 B-cols). A-rows 0..127 = Wkv K rows m*128.. (heads 2m,2m+1);
// A-rows 128..255 = Wkv V rows 1024+m*128.. . B = xb s-cols ntile*128.. .
// Pipeline: 3 buffers x (A 256x32 + B 128x32) = 72KB, 3 gll16/thread/step, vmcnt(3).
// Epilogue: bias+elu -> bf16 -> LDS [256][CLP]; KV_h = Kp_h @ Vp_h^T (K=128) via MFMA;
// atomicAdd to kvb; Ksum via 4-lane partials + shfl + atomics.
__global__ __launch_bounds__(512, 4) void kvproj(
    const bf16* __restrict__ Wkv, const bf16* __restrict__ xb,
    const float* __restrict__ bk, const float* __restrict__ bv,
    float* __restrict__ kvb, float* __restrict__ ksb) {
  __shared__ __align__(16) bf16 sm[3 * 12288];   // 72 KB
  const int tid  = threadIdx.x;
  const int wid  = tid >> 6;
  const int lane = tid & 63;
  const int wm = wid >> 1, wn = wid & 1;
  const int m = blockIdx.x, ntile = blockIdx.y;
  const int lr = lane >> 2;
  const int lc = lane & 3;
  const int ssrc = (((lc << 4) ^ (((lr >> 1) & 3) << 4)) >> 1);
  const int fhalf = (lane >> 4) << 4;

  const bf16* KA = Wkv + (size_t)(m * 128) * KDIM;            // K panel
  const bf16* VA = Wkv + (size_t)(1024 + m * 128) * KDIM;     // V panel
  const bf16* BB = xb + (size_t)(ntile * 128) * KDIM;

  // wave stages A segs {2w,2w+1} (of 16) and B seg {w} (of 8)
  const bf16* ap[2]; const bf16* bp; int sda[2], sdb;
  #pragma unroll
  for (int i = 0; i < 2; ++i) {
    int seg = (wid << 1) | i;                 // 0..15
    const bf16* base = (seg < 8) ? KA : VA;
    ap[i] = base + (size_t)((seg & 7) * 16 + lr) * KDIM + ssrc;
    sda[i] = seg * 512;
  }
  bp = BB + (size_t)(wid * 16 + lr) * KDIM + ssrc;
  sdb = 8192 + wid * 512;

  // prologue: stage steps 0,1
  #pragma unroll
  for (int i = 0; i < 2; ++i) gll16(ap[i], sm + sda[i]);
  gll16(bp, sm + sdb);
  #pragma unroll
  for (int i = 0; i < 2; ++i) gll16(ap[i] + 32, sm + 12288 + sda[i]);
  gll16(bp + 32, sm + 12288 + sdb);
  asm volatile("s_waitcnt vmcnt(3)" ::: "memory");
  __builtin_amdgcn_s_barrier();
  asm volatile("" ::: "memory");

  f32x4 acc[4][4] = {};
  int cur = 0;
  for (int t = 0; t < NTK; ++t) {
    const bf16* As = sm + cur * 12288;
    const bf16* Bs = As + 8192;

    bf16x8 af[4], bfv[4];
    #pragma unroll
    for (int mm = 0; mm < 4; ++mm) {
      int R = wm*64 + mm*16 + (lane & 15);
      af[mm] = *(const bf16x8*)((const char*)As + R*64 + (fhalf ^ (((R >> 1) & 3) << 4)));
    }
    #pragma unroll
    for (int nn = 0; nn < 4; ++nn) {
      int R = wn*64 + nn*16 + (lane & 15);
      bfv[nn] = *(const bf16x8*)((const char*)Bs + R*64 + (fhalf ^ (((R >> 1) & 3) << 4)));
    }

    if (t + 2 < NTK) {
      int nx2 = cur + 2; if (nx2 >= 3) nx2 -= 3;
      bf16* wb = sm + nx2 * 12288;
      const int ko = (t + 2) * 32;
      #pragma unroll
      for (int i = 0; i < 2; ++i) gll16(ap[i] + ko, wb + sda[i]);
      gll16(bp + ko, wb + sdb);
    }

    #pragma unroll
    for (int mm = 0; mm < 4; ++mm)
      #pragma unroll
      for (int nn = 0; nn < 4; ++nn)
        acc[mm][nn] = MFMA16(af[mm], bfv[nn], acc[mm][nn]);

    if (t < NTK - 2)       asm volatile("s_waitcnt vmcnt(3)" ::: "memory");
    else if (t == NTK - 2) asm volatile("s_waitcnt vmcnt(0)" ::: "memory");
    if (t < NTK - 1) {
      __builtin_amdgcn_s_barrier();
      asm volatile("" ::: "memory");
    }
    cur = (cur == 2) ? 0 : cur + 1;
  }
  __syncthreads();   // all LDS reads done before C-store reuses sm

  // ---- C tile (bias + elu on K rows) -> LDS [256][CLP] bf16 ----
  bf16* CL = sm;
  #pragma unroll
  for (int mm = 0; mm < 4; ++mm) {
    #pragma unroll
    for (int i = 0; i < 4; ++i) {
      int ra = wm*64 + mm*16 + ((lane >> 4) << 2) + i;
      float bias = (ra < 128) ? bk[m*128 + ra] : bv[m*128 + ra - 128];
      #pragma unroll
      for (int nn = 0; nn < 4; ++nn) {
        int cb = wn*64 + nn*16 + (lane & 15);
        float v = acc[mm][nn][i] + bias;
        if (ra < 128) v = (v > 0.f) ? v + 1.f : __expf(v);   // elu(k)+1
        CL[ra*CLP + cb] = (bf16)v;
      }
    }
  }
  __syncthreads();

  // ---- KV_h = Kp_h @ Vp_h^T over this 128-s block, K=128 ----
  const int hl = wid >> 2;          // head-local 0..1
  const int ww = wid & 3;           // row-slice within head
  const int bh = (ntile >> 5) * 16 + 2*m + hl;
  f32x4 acc2[4] = {};
  #pragma unroll
  for (int ks = 0; ks < 4; ++ks) {
    bf16x8 akv = *(const bf16x8*)(CL + (hl*64 + ww*16 + (lane & 15))*CLP + ks*32 + ((lane >> 4) << 3));
    #pragma unroll
    for (int nn = 0; nn < 4; ++nn) {
      bf16x8 bkv = *(const bf16x8*)(CL + (128 + hl*64 + nn*16 + (lane & 15))*CLP + ks*32 + ((lane >> 4) << 3));
      acc2[nn] = MFMA16(akv, bkv, acc2[nn]);
    }
  }
  float* KVh = kvb + (size_t)bh * 4096;
  #pragma unroll
  for (int nn = 0; nn < 4; ++nn)
    #pragma unroll
    for (int i = 0; i < 4; ++i) {
      int dd = ww*16 + ((lane >> 4) << 2) + i;
      int vv = nn*16 + (lane & 15);
      atomicAdd(&KVh[dd*64 + vv], acc2[nn][i]);
    }

  // ---- Ksum over K rows ----
  {
    int rid = tid >> 2, part = tid & 3;        // rid 0..127
    float s = 0.f;
    #pragma unroll
    for (int j = 0; j < 32; ++j) s += (float)CL[rid*CLP + part*32 + j];
    s += __shfl_xor(s, 1);
    s += __shfl_xor(s, 2);
    if (part == 0) {
      int hh = rid >> 6, d = rid & 63;
      atomicAdd(&ksb[((ntile >> 5) * 16 + 2*m + hh)*64 + d], s);
    }
  }
}

// ---------------- out_pre = (Qp @ KV) / Z ----------------
__global__ __launch_bounds__(256) void attn_out(const bf16* __restrict__ QP,
                                                const float* __restrict__ KVg,
                                                const float* __restrict__ Ksumg,
                                                bf16* __restrict__ OP) {
  const int head = blockIdx.x, stile = blockIdx.y;
  const int b = head >> 4, hh = head & 15;
  const int tid = threadIdx.x;
  const int wid = tid >> 6, lane = tid & 63;
  const int s0 = stile * 128;
  __shared__ __align__(16) bf16 Qs[128*64];
  __shared__ __align__(16) bf16 KVt[64*64];
  __shared__ float ksum_s[64];
  __shared__ float rZ[128];

  const float* KVh = KVg + (size_t)head*4096;
  #pragma unroll
  for (int i = 0; i < 16; ++i) {
    int idx = i*256 + tid;
    int dd = idx >> 6, vv = idx & 63;
    KVt[vv*64 + dd] = (bf16)KVh[idx];
  }
  if (tid < 64) ksum_s[tid] = Ksumg[head*64 + tid];
  #pragma unroll
  for (int p = 0; p < 4; ++p) {
    int row = p*32 + wid*8 + (lane >> 3);
    gll16(QP + ((size_t)(b*S_LEN + s0 + row))*DMODEL + hh*64 + ((lane&7)<<3),
          Qs + (p*32 + wid*8)*64);
  }
  __syncthreads();

  if (tid < 128) {
    float z = 0.f;
    #pragma unroll
    for (int dd = 0; dd < 64; ++dd) z += (float)Qs[tid*64 + dd] * ksum_s[dd];
    rZ[tid] = 1.f / (z + 1e-6f);
  }
  __syncthreads();

  f32x4 acc[2][4] = {};
  #pragma unroll
  for (int ksb2 = 0; ksb2 < 2; ++ksb2) {
    bf16x8 af[2], bv[4];
    #pragma unroll
    for (int m = 0; m < 2; ++m)
      af[m] = *(const bf16x8*)(Qs + (wid*32 + m*16 + (lane & 15))*64 + ksb2*32 + ((lane>>4)<<3));
    #pragma unroll
    for (int n = 0; n < 4; ++n)
      bv[n] = *(const bf16x8*)(KVt + (n*16 + (lane & 15))*64 + ksb2*32 + ((lane>>4)<<3));
    #pragma unroll
    for (int m = 0; m < 2; ++m)
      #pragma unroll
      for (int n = 0; n < 4; ++n)
        acc[m][n] = MFMA16(af[m], bv[n], acc[m][n]);
  }

  #pragma unroll
  for (int m = 0; m < 2; ++m)
    #pragma unroll
    for (int n = 0; n < 4; ++n)
      #pragma unroll
      for (int i = 0; i < 4; ++i) {
        int row = wid*32 + m*16 + ((lane >> 4) << 2) + i;
        int vv  = n*16 + (lane & 15);
        float val = acc[m][n][i] * rZ[row];
        OP[((size_t)((s0+row)*BATCHN + b))*DMODEL + hh*64 + vv] = (bf16)val;
      }
}

// ---------------- launch ----------------
extern "C" void kernel_launch(void* const* d_in, const int* in_sizes, int n_in,
                              void* d_out, int out_size, void* d_ws, size_t ws_size,
                              hipStream_t stream) {
  const float* h  = (const float*)d_in[0];
  const float* x  = (const float*)d_in[1];
  const float* Wq = (const float*)d_in[2];
  const float* bq = (const float*)d_in[3];
  const float* Wk = (const float*)d_in[4];
  const float* bk = (const float*)d_in[5];
  const float* Wv = (const float*)d_in[6];
  const float* bv = (const float*)d_in[7];
  const float* Wo = (const float*)d_in[8];
  const float* bo = (const float*)d_in[9];

  char* ws = (char*)d_ws;
  bf16*  hb   = (bf16*)(ws);                    // 33,554,432 B  [B][S][D]
  bf16*  xb   = (bf16*)(ws + 33554432);         // 33,554,432 B  [B][S][D]
  bf16*  wcat = (bf16*)(ws + 67108864);         //  6,291,456 B  Wq|Wk|Wv [3072][1024]
  bf16*  wob  = (bf16*)(ws + 73400320);         //  2,097,152 B  [1024][1024]
  bf16*  qp   = (bf16*)(ws + 75497472);         // 33,554,432 B  [16384 b*s][1024]
  float* kvb  = (float*)(ws + 109051904);       //  1,048,576 B  [64][64][64]
  float* ksb  = (float*)(ws + 110100480);       //     16,384 B  [64][64]
  bf16*  op   = (bf16*)(ws + 110116864);        // 33,554,432 B  [16384 s*b][1024]
  // total 143,671,296 B

  cast_perm<<<dim3(4096), 256, 0, stream>>>(h, x, hb, xb);
  cast_w<<<dim3(2048), 256, 0, stream>>>(Wq, Wk, Wv, Wo, wcat);

  hipMemsetAsync(kvb, 0, 1048576 + 16384, stream);

  kvproj<<<dim3(8, 128), 512, 0, stream>>>(wcat + 1048576, xb, bk, bv, kvb, ksb);
  gemm_bt<0><<<dim3(128, 8), 256, 0, stream>>>(hb, wcat, bq, qp);
  attn_out<<<dim3(64, 32), 256, 0, stream>>>(qp, kvb, ksb, op);
  gemm_bt<2><<<dim3(128, 8), 256, 0, stream>>>(op, wob, bo, d_out);
}

// Round 11
// 242.521 us; speedup vs baseline: 1.2007x; 1.0603x over previous
//
#include <hip/hip_runtime.h>
#include <hip/hip_bf16.h>
#include <cstdint>
#include <cstddef>

#define S_LEN   4096
#define BATCHN  4
#define DMODEL  1024
#define NHEADS  16
#define HDIM    64
#define MROWS   (S_LEN*BATCHN)   // 16384
#define KDIM    1024
#define NTK     (KDIM/32)        // 32 K-steps
#define CLP     136              // padded C-tile pitch (elements)

typedef __bf16 bf16;
typedef bf16 bf16x8 __attribute__((ext_vector_type(8)));
typedef bf16 bf16x4 __attribute__((ext_vector_type(4)));
typedef float f32x4 __attribute__((ext_vector_type(4)));

#define MFMA16(a,b,c) __builtin_amdgcn_mfma_f32_16x16x32_bf16(a,b,c,0,0,0)

__device__ __forceinline__ void gll16(const void* g, void* l) {
  __builtin_amdgcn_global_load_lds((const __attribute__((address_space(1))) unsigned*)g,
                                   (__attribute__((address_space(3))) unsigned*)l,
                                   16, 0, 0);
}

// ---------------- cast fp32 [S][B][D] -> bf16 [B][S][D] for h and x ----------------
__global__ __launch_bounds__(256) void cast_perm(const float* __restrict__ h,
                                                 const float* __restrict__ x,
                                                 bf16* __restrict__ hb,
                                                 bf16* __restrict__ xb) {
  const int n = MROWS * KDIM;
  int stride = gridDim.x * blockDim.x * 4;
  for (int i = (blockIdx.x * blockDim.x + threadIdx.x) * 4; i < n; i += stride) {
    int s = i >> 12, b = (i >> 10) & 3, d = i & 1023;
    size_t o = ((size_t)(b * S_LEN + s) << 10) | d;
    float4 f = *(const float4*)(h + i);
    bf16x4 u; u[0]=(bf16)f.x; u[1]=(bf16)f.y; u[2]=(bf16)f.z; u[3]=(bf16)f.w;
    *(bf16x4*)(hb + o) = u;
    float4 g = *(const float4*)(x + i);
    bf16x4 v; v[0]=(bf16)g.x; v[1]=(bf16)g.y; v[2]=(bf16)g.z; v[3]=(bf16)g.w;
    *(bf16x4*)(xb + o) = v;
  }
}

// all four weight matrices -> contiguous wcat(3M: Wq|Wk|Wv) | wob(1M)
__global__ __launch_bounds__(256) void cast_w(const float* __restrict__ Wq,
                                              const float* __restrict__ Wk,
                                              const float* __restrict__ Wv,
                                              const float* __restrict__ Wo,
                                              bf16* __restrict__ dst) {
  const int n = 4 * 1048576;
  int stride = gridDim.x * blockDim.x * 4;
  for (int i = (blockIdx.x * blockDim.x + threadIdx.x) * 4; i < n; i += stride) {
    int r = i >> 20;
    const float* src = (r < 1) ? (Wq + i) : (r < 2) ? (Wk + i - 1048576)
                     : (r < 3) ? (Wv + i - 2097152) : (Wo + i - 3145728);
    float4 f = *(const float4*)src;
    bf16x4 o; o[0]=(bf16)f.x; o[1]=(bf16)f.y; o[2]=(bf16)f.z; o[3]=(bf16)f.w;
    *(bf16x4*)(dst + i) = o;
  }
}

// ---------------- shared GEMM body: 3-buffer pipeline, counted vmcnt, XOR swizzle -----
struct GemmAcc { f32x4 a[4][4]; };

__device__ __forceinline__ void gemm_tile(const bf16* __restrict__ A,
                                          const bf16* __restrict__ Bw,
                                          size_t arow0, size_t brow0,
                                          bf16* sm, GemmAcc& G) {
  const int tid  = threadIdx.x;
  const int wid  = tid >> 6;
  const int lane = tid & 63;
  const int wm = wid >> 1, wn = wid & 1;
  const int lr = lane >> 2;
  const int lc = lane & 3;
  const int ssrc = (((lc << 4) ^ (((lr >> 1) & 3) << 4)) >> 1);
  const int fhalf = (lane >> 4) << 4;

  const bf16* ap[2]; const bf16* bp[2]; int sdo[2];
  #pragma unroll
  for (int i = 0; i < 2; ++i) {
    int seg = (wid << 1) | i;
    ap[i] = A  + (arow0 + seg*16 + lr) * KDIM + ssrc;
    bp[i] = Bw + (brow0 + seg*16 + lr) * KDIM + ssrc;
    sdo[i] = seg * 512;
  }

  #pragma unroll
  for (int i = 0; i < 2; ++i) { gll16(ap[i],      sm + sdo[i]); gll16(bp[i],      sm + 4096 + sdo[i]); }
  #pragma unroll
  for (int i = 0; i < 2; ++i) { gll16(ap[i] + 32, sm + 8192 + sdo[i]); gll16(bp[i] + 32, sm + 12288 + sdo[i]); }
  asm volatile("s_waitcnt vmcnt(4)" ::: "memory");
  __builtin_amdgcn_s_barrier();
  asm volatile("" ::: "memory");

  int cur = 0;
  for (int t = 0; t < NTK; ++t) {
    const bf16* As = sm + cur * 8192;
    const bf16* Bs = As + 4096;

    bf16x8 af[4], bfv[4];
    #pragma unroll
    for (int m = 0; m < 4; ++m) {
      int R = wm*64 + m*16 + (lane & 15);
      af[m] = *(const bf16x8*)((const char*)As + R*64 + (fhalf ^ (((R >> 1) & 3) << 4)));
    }
    #pragma unroll
    for (int n = 0; n < 4; ++n) {
      int R = wn*64 + n*16 + (lane & 15);
      bfv[n] = *(const bf16x8*)((const char*)Bs + R*64 + (fhalf ^ (((R >> 1) & 3) << 4)));
    }

    if (t + 2 < NTK) {
      int nx2 = cur + 2; if (nx2 >= 3) nx2 -= 3;
      bf16* wbA = sm + nx2 * 8192;
      const int ko = (t + 2) * 32;
      #pragma unroll
      for (int i = 0; i < 2; ++i) {
        gll16(ap[i] + ko, wbA + sdo[i]);
        gll16(bp[i] + ko, wbA + 4096 + sdo[i]);
      }
    }

    #pragma unroll
    for (int m = 0; m < 4; ++m)
      #pragma unroll
      for (int n = 0; n < 4; ++n)
        G.a[m][n] = MFMA16(af[m], bfv[n], G.a[m][n]);

    if (t < NTK - 2)       asm volatile("s_waitcnt vmcnt(4)" ::: "memory");
    else if (t == NTK - 2) asm volatile("s_waitcnt vmcnt(0)" ::: "memory");
    if (t < NTK - 1) {
      __builtin_amdgcn_s_barrier();
      asm volatile("" ::: "memory");
    }
    cur = (cur == 2) ? 0 : cur + 1;
  }
}

// ---------------- Q projection + elu + Z + scale: qs = (elu(h@Wq^T+bq)+1)/Z ----------
// grid (128 mtile over b*4096+s rows, 8 ntile). Each wave's 64-col block = one head
// hgg = (mtile>>5)*16 + ntile*2 + wn. Z reduced in-register (4 cols/lane + shfl_xor).
__global__ __launch_bounds__(256) void q_gemm(
    const bf16* __restrict__ A, const bf16* __restrict__ Bw,
    const float* __restrict__ bq, const float* __restrict__ Ksumg,
    bf16* __restrict__ qs) {
  __shared__ __align__(16) bf16 sm[3 * 8192];
  const int tid  = threadIdx.x;
  const int wid  = tid >> 6;
  const int lane = tid & 63;
  const int wm = wid >> 1, wn = wid & 1;
  const int mtile = blockIdx.x, ntile = blockIdx.y;

  GemmAcc G = {};
  gemm_tile(A, Bw, (size_t)mtile * 128, (size_t)ntile * 128, sm, G);

  const int hgg = (mtile >> 5) * 16 + ntile * 2 + wn;   // global (b,h)
  float ksl[4], bql[4];
  #pragma unroll
  for (int n = 0; n < 4; ++n) {
    ksl[n] = Ksumg[hgg*64 + n*16 + (lane & 15)];
    bql[n] = bq[ntile*128 + wn*64 + n*16 + (lane & 15)];
  }

  #pragma unroll
  for (int m = 0; m < 4; ++m) {
    #pragma unroll
    for (int i = 0; i < 4; ++i) {
      int row = mtile*128 + wm*64 + m*16 + ((lane >> 4) << 2) + i;
      float v[4], zp = 0.f;
      #pragma unroll
      for (int n = 0; n < 4; ++n) {
        float t = G.a[m][n][i] + bql[n];
        t = (t > 0.f) ? t + 1.f : __expf(t);     // elu+1
        v[n] = t;
        zp += t * ksl[n];
      }
      zp += __shfl_xor(zp, 1);
      zp += __shfl_xor(zp, 2);
      zp += __shfl_xor(zp, 4);
      zp += __shfl_xor(zp, 8);
      float rz = 1.f / (zp + 1e-6f);
      #pragma unroll
      for (int n = 0; n < 4; ++n) {
        int col = ntile*128 + wn*64 + n*16 + (lane & 15);
        qs[(size_t)row*DMODEL + col] = (bf16)(v[n] * rz);
      }
    }
  }
}

// ---------------- output GEMM: d_out[s*4+b] = qs[b*4096+s] @ B2_b^T + bo -------------
__global__ __launch_bounds__(256) void out_gemm(const bf16* __restrict__ qsA,
                                                const bf16* __restrict__ B2,
                                                const float* __restrict__ bo,
                                                float* __restrict__ Cout) {
  __shared__ __align__(16) bf16 sm[3 * 8192];
  const int tid  = threadIdx.x;
  const int wid  = tid >> 6;
  const int lane = tid & 63;
  const int wm = wid >> 1, wn = wid & 1;
  const int mtile = blockIdx.x, ntile = blockIdx.y;
  const bf16* Bw = B2 + (size_t)(mtile >> 5) * 1048576;   // per-batch B2

  GemmAcc G = {};
  gemm_tile(qsA, Bw, (size_t)mtile * 128, (size_t)ntile * 128, sm, G);

  #pragma unroll
  for (int m = 0; m < 4; ++m) {
    int rowb = mtile*128 + wm*64 + m*16 + ((lane >> 4) << 2);
    #pragma unroll
    for (int n = 0; n < 4; ++n) {
      int col = ntile*128 + wn*64 + n*16 + (lane & 15);
      float bias = bo[col];
      #pragma unroll
      for (int i = 0; i < 4; ++i) {
        int g = rowb + i;                               // b*4096 + s
        int orow = ((g & 4095) << 2) | (g >> 12);       // s*4 + b
        Cout[(size_t)orow*DMODEL + col] = G.a[m][n][i] + bias;
      }
    }
  }
}

// ---------------- fused KV projection + KV/Ksum reduction (unchanged from R10) --------
__global__ __launch_bounds__(512, 4) void kvproj(
    const bf16* __restrict__ Wkv, const bf16* __restrict__ xb,
    const float* __restrict__ bk, const float* __restrict__ bv,
    float* __restrict__ kvb, float* __restrict__ ksb) {
  __shared__ __align__(16) bf16 sm[3 * 12288];   // 72 KB
  const int tid  = threadIdx.x;
  const int wid  = tid >> 6;
  const int lane = tid & 63;
  const int wm = wid >> 1, wn = wid & 1;
  const int m = blockIdx.x, ntile = blockIdx.y;
  const int lr = lane >> 2;
  const int lc = lane & 3;
  const int ssrc = (((lc << 4) ^ (((lr >> 1) & 3) << 4)) >> 1);
  const int fhalf = (lane >> 4) << 4;

  const bf16* KA = Wkv + (size_t)(m * 128) * KDIM;
  const bf16* VA = Wkv + (size_t)(1024 + m * 128) * KDIM;
  const bf16* BB = xb + (size_t)(ntile * 128) * KDIM;

  const bf16* ap[2]; const bf16* bp; int sda[2], sdb;
  #pragma unroll
  for (int i = 0; i < 2; ++i) {
    int seg = (wid << 1) | i;
    const bf16* base = (seg < 8) ? KA : VA;
    ap[i] = base + (size_t)((seg & 7) * 16 + lr) * KDIM + ssrc;
    sda[i] = seg * 512;
  }
  bp = BB + (size_t)(wid * 16 + lr) * KDIM + ssrc;
  sdb = 8192 + wid * 512;

  #pragma unroll
  for (int i = 0; i < 2; ++i) gll16(ap[i], sm + sda[i]);
  gll16(bp, sm + sdb);
  #pragma unroll
  for (int i = 0; i < 2; ++i) gll16(ap[i] + 32, sm + 12288 + sda[i]);
  gll16(bp + 32, sm + 12288 + sdb);
  asm volatile("s_waitcnt vmcnt(3)" ::: "memory");
  __builtin_amdgcn_s_barrier();
  asm volatile("" ::: "memory");

  f32x4 acc[4][4] = {};
  int cur = 0;
  for (int t = 0; t < NTK; ++t) {
    const bf16* As = sm + cur * 12288;
    const bf16* Bs = As + 8192;

    bf16x8 af[4], bfv[4];
    #pragma unroll
    for (int mm = 0; mm < 4; ++mm) {
      int R = wm*64 + mm*16 + (lane & 15);
      af[mm] = *(const bf16x8*)((const char*)As + R*64 + (fhalf ^ (((R >> 1) & 3) << 4)));
    }
    #pragma unroll
    for (int nn = 0; nn < 4; ++nn) {
      int R = wn*64 + nn*16 + (lane & 15);
      bfv[nn] = *(const bf16x8*)((const char*)Bs + R*64 + (fhalf ^ (((R >> 1) & 3) << 4)));
    }

    if (t + 2 < NTK) {
      int nx2 = cur + 2; if (nx2 >= 3) nx2 -= 3;
      bf16* wb = sm + nx2 * 12288;
      const int ko = (t + 2) * 32;
      #pragma unroll
      for (int i = 0; i < 2; ++i) gll16(ap[i] + ko, wb + sda[i]);
      gll16(bp + ko, wb + sdb);
    }

    #pragma unroll
    for (int mm = 0; mm < 4; ++mm)
      #pragma unroll
      for (int nn = 0; nn < 4; ++nn)
        acc[mm][nn] = MFMA16(af[mm], bfv[nn], acc[mm][nn]);

    if (t < NTK - 2)       asm volatile("s_waitcnt vmcnt(3)" ::: "memory");
    else if (t == NTK - 2) asm volatile("s_waitcnt vmcnt(0)" ::: "memory");
    if (t < NTK - 1) {
      __builtin_amdgcn_s_barrier();
      asm volatile("" ::: "memory");
    }
    cur = (cur == 2) ? 0 : cur + 1;
  }
  __syncthreads();

  bf16* CL = sm;
  #pragma unroll
  for (int mm = 0; mm < 4; ++mm) {
    #pragma unroll
    for (int i = 0; i < 4; ++i) {
      int ra = wm*64 + mm*16 + ((lane >> 4) << 2) + i;
      float bias = (ra < 128) ? bk[m*128 + ra] : bv[m*128 + ra - 128];
      #pragma unroll
      for (int nn = 0; nn < 4; ++nn) {
        int cb = wn*64 + nn*16 + (lane & 15);
        float v = acc[mm][nn][i] + bias;
        if (ra < 128) v = (v > 0.f) ? v + 1.f : __expf(v);   // elu(k)+1
        CL[ra*CLP + cb] = (bf16)v;
      }
    }
  }
  __syncthreads();

  const int hl = wid >> 2;
  const int ww = wid & 3;
  const int bh = (ntile >> 5) * 16 + 2*m + hl;
  f32x4 acc2[4] = {};
  #pragma unroll
  for (int ks = 0; ks < 4; ++ks) {
    bf16x8 akv = *(const bf16x8*)(CL + (hl*64 + ww*16 + (lane & 15))*CLP + ks*32 + ((lane >> 4) << 3));
    #pragma unroll
    for (int nn = 0; nn < 4; ++nn) {
      bf16x8 bkv = *(const bf16x8*)(CL + (128 + hl*64 + nn*16 + (lane & 15))*CLP + ks*32 + ((lane >> 4) << 3));
      acc2[nn] = MFMA16(akv, bkv, acc2[nn]);
    }
  }
  float* KVh = kvb + (size_t)bh * 4096;
  #pragma unroll
  for (int nn = 0; nn < 4; ++nn)
    #pragma unroll
    for (int i = 0; i < 4; ++i) {
      int dd = ww*16 + ((lane >> 4) << 2) + i;
      int vv = nn*16 + (lane & 15);
      atomicAdd(&KVh[dd*64 + vv], acc2[nn][i]);
    }

  {
    int rid = tid >> 2, part = tid & 3;
    float s = 0.f;
    #pragma unroll
    for (int j = 0; j < 32; ++j) s += (float)CL[rid*CLP + part*32 + j];
    s += __shfl_xor(s, 1);
    s += __shfl_xor(s, 2);
    if (part == 0) {
      int hh = rid >> 6, d = rid & 63;
      atomicAdd(&ksb[((ntile >> 5) * 16 + 2*m + hh)*64 + d], s);
    }
  }
}

// ---------------- B2_b[o][h*64+d] = sum_v KV_{b,h}[d][v] * Wo[o][h*64+v] -------------
// grid (8 mtile over o, 64 bh). Structure mirrors attn_out's verified MFMA layout.
__global__ __launch_bounds__(256) void w2_gemm(const bf16* __restrict__ wob,
                                               const float* __restrict__ kvb,
                                               bf16* __restrict__ B2) {
  const int mtile = blockIdx.x, bh = blockIdx.y;
  const int b = bh >> 4, hh = bh & 15;
  const int tid = threadIdx.x;
  const int wid = tid >> 6, lane = tid & 63;
  __shared__ __align__(16) bf16 Wos[128*64];
  __shared__ __align__(16) bf16 KVs[64*64];     // [d][v]

  #pragma unroll
  for (int it = 0; it < 4; ++it) {
    int idx = it*256 + tid;                     // 1024 chunks of 8
    int row = idx >> 3, c = (idx & 7) << 3;
    *(bf16x8*)(Wos + row*64 + c) =
      *(const bf16x8*)(wob + (size_t)(mtile*128 + row)*DMODEL + hh*64 + c);
  }
  const float* KVh = kvb + (size_t)bh * 4096;
  #pragma unroll
  for (int it = 0; it < 16; ++it) {
    int idx = it*256 + tid;
    KVs[idx] = (bf16)KVh[idx];
  }
  __syncthreads();

  f32x4 acc[2][4] = {};
  #pragma unroll
  for (int ks = 0; ks < 2; ++ks) {
    bf16x8 af[2], bv[4];
    #pragma unroll
    for (int m = 0; m < 2; ++m)
      af[m] = *(const bf16x8*)(Wos + (wid*32 + m*16 + (lane & 15))*64 + ks*32 + ((lane>>4)<<3));
    #pragma unroll
    for (int n = 0; n < 4; ++n)
      bv[n] = *(const bf16x8*)(KVs + (n*16 + (lane & 15))*64 + ks*32 + ((lane>>4)<<3));
    #pragma unroll
    for (int m = 0; m < 2; ++m)
      #pragma unroll
      for (int n = 0; n < 4; ++n)
        acc[m][n] = MFMA16(af[m], bv[n], acc[m][n]);
  }

  bf16* B2b = B2 + (size_t)b * 1048576;
  #pragma unroll
  for (int m = 0; m < 2; ++m)
    #pragma unroll
    for (int n = 0; n < 4; ++n)
      #pragma unroll
      for (int i = 0; i < 4; ++i) {
        int orow = mtile*128 + wid*32 + m*16 + ((lane >> 4) << 2) + i;
        int dd   = n*16 + (lane & 15);
        B2b[(size_t)orow*DMODEL + hh*64 + dd] = (bf16)acc[m][n][i];
      }
}

// ---------------- launch ----------------
extern "C" void kernel_launch(void* const* d_in, const int* in_sizes, int n_in,
                              void* d_out, int out_size, void* d_ws, size_t ws_size,
                              hipStream_t stream) {
  const float* h  = (const float*)d_in[0];
  const float* x  = (const float*)d_in[1];
  const float* Wq = (const float*)d_in[2];
  const float* bq = (const float*)d_in[3];
  const float* Wk = (const float*)d_in[4];
  const float* bk = (const float*)d_in[5];
  const float* Wv = (const float*)d_in[6];
  const float* bv = (const float*)d_in[7];
  const float* Wo = (const float*)d_in[8];
  const float* bo = (const float*)d_in[9];

  char* ws = (char*)d_ws;
  bf16*  hb   = (bf16*)(ws);                    // 33,554,432 B  [B][S][D]
  bf16*  xb   = (bf16*)(ws + 33554432);         // 33,554,432 B  [B][S][D]
  bf16*  wcat = (bf16*)(ws + 67108864);         //  6,291,456 B  Wq|Wk|Wv [3072][1024]
  bf16*  wob  = (bf16*)(ws + 73400320);         //  2,097,152 B  [1024][1024]
  bf16*  qs   = (bf16*)(ws + 75497472);         // 33,554,432 B  [16384 b*s][1024]
  float* kvb  = (float*)(ws + 109051904);       //  1,048,576 B  [64][64][64]
  float* ksb  = (float*)(ws + 110100480);       //     16,384 B  [64][64]
  bf16*  B2   = (bf16*)(ws + 110116864);        //  8,388,608 B  [4][1024][1024]
  // total 118,505,472 B

  cast_perm<<<dim3(4096), 256, 0, stream>>>(h, x, hb, xb);
  cast_w<<<dim3(2048), 256, 0, stream>>>(Wq, Wk, Wv, Wo, wcat);

  hipMemsetAsync(kvb, 0, 1048576 + 16384, stream);

  kvproj<<<dim3(8, 128), 512, 0, stream>>>(wcat + 1048576, xb, bk, bv, kvb, ksb);
  w2_gemm<<<dim3(8, 64), 256, 0, stream>>>(wob, kvb, B2);
  q_gemm<<<dim3(128, 8), 256, 0, stream>>>(hb, wcat, bq, ksb, qs);
  out_gemm<<<dim3(128, 8), 256, 0, stream>>>(qs, B2, bo, (float*)d_out);
}